// Round 2
// baseline (369.965 us; speedup 1.0000x reference)
//
#include <hip/hip_runtime.h>
#include <stdint.h>

#define NUM_B 128
#define NUM_P 8732
#define NUM_G 16
#define NUM_C 21
#define THR 0.5f
#define SEL_T 512
#define SEL_W (SEL_T / 64)

struct Globals {
    float loss_l;
    float loss_c;
    float npos;
    unsigned int ticket;
};

__device__ __forceinline__ unsigned int f2u(float f) {
    unsigned int b = __float_as_uint(f);
    return (b & 0x80000000u) ? ~b : (b | 0x80000000u);
}
__device__ __forceinline__ float u2f(unsigned int u) {
    unsigned int b = (u & 0x80000000u) ? (u & 0x7FFFFFFFu) : ~u;
    return __uint_as_float(b);
}

// ---------------------------------------------------------------- init ws
__global__ void init_kernel(unsigned long long* __restrict__ bp,
                            unsigned int* __restrict__ row_pos,
                            Globals* __restrict__ g) {
    int idx = blockIdx.x * blockDim.x + threadIdx.x;
    if (idx < NUM_B * NUM_G) bp[idx] = 0ull;
    if (idx < NUM_B) row_pos[idx] = 0u;
    if (idx == 0) { g->loss_l = 0.f; g->loss_c = 0.f; g->npos = 0.f; g->ticket = 0u; }
}

// ---------------------------------------------------------------- matching
__global__ void __launch_bounds__(256) match_kernel(
        const float* __restrict__ priors,
        const float* __restrict__ targets,
        float* __restrict__ bto, unsigned char* __restrict__ bti,
        unsigned long long* __restrict__ bp) {
    int b   = blockIdx.y;
    int tid = threadIdx.x;
    int i   = blockIdx.x * blockDim.x + tid;
    int lane = tid & 63;

    __shared__ float tg[NUM_G][4];
    __shared__ float tarea[NUM_G];
    __shared__ unsigned long long sbp[NUM_G];

    if (tid < NUM_G * 4) {
        int j = tid >> 2, d = tid & 3;
        tg[j][d] = targets[(size_t)(b * NUM_G + j) * 11 + d];
    }
    if (tid < NUM_G) sbp[tid] = 0ull;
    __syncthreads();
    if (tid < NUM_G) tarea[tid] = (tg[tid][2] - tg[tid][0]) * (tg[tid][3] - tg[tid][1]);
    __syncthreads();

    float iou[NUM_G];
    bool valid = (i < NUM_P);
    float best = -1.0f; int bestj = 0;
    if (valid) {
        float pcx = priors[i * 4 + 0], pcy = priors[i * 4 + 1];
        float pw  = priors[i * 4 + 2], ph  = priors[i * 4 + 3];
        float bx1 = pcx - pw * 0.5f, by1 = pcy - ph * 0.5f;
        float bx2 = pcx + pw * 0.5f, by2 = pcy + ph * 0.5f;
        float areaB = (bx2 - bx1) * (by2 - by1);
        #pragma unroll
        for (int j = 0; j < NUM_G; ++j) {
            float dx = fminf(tg[j][2], bx2) - fmaxf(tg[j][0], bx1);
            float dy = fminf(tg[j][3], by2) - fmaxf(tg[j][1], by1);
            dx = fmaxf(dx, 0.f); dy = fmaxf(dy, 0.f);
            float inter = dx * dy;
            iou[j] = inter / (tarea[j] + areaB - inter);
            if (iou[j] > best) { best = iou[j]; bestj = j; }  // strict > => first-index
        }
        bto[(size_t)b * NUM_P + i] = best;
        bti[(size_t)b * NUM_P + i] = (unsigned char)bestj;
    } else {
        #pragma unroll
        for (int j = 0; j < NUM_G; ++j) iou[j] = -1.0f;
    }

    // per-gt wave max (float shfl) + ballot leader -> one 64b atomic per gt per wave
    #pragma unroll
    for (int j = 0; j < NUM_G; ++j) {
        float m = iou[j];
        #pragma unroll
        for (int s = 1; s < 64; s <<= 1)
            m = fmaxf(m, __shfl_xor(m, s, 64));
        unsigned long long tied = __ballot(iou[j] == m);
        int leader = __ffsll((unsigned long long)tied) - 1;
        if (lane == leader && valid) {
            unsigned long long pk = ((unsigned long long)f2u(iou[j]) << 32) |
                                    (unsigned long long)(0xFFFFFFFFu - (unsigned int)i);
            atomicMax(&sbp[j], pk);
        }
    }
    __syncthreads();
    if (tid < NUM_G) atomicMax(&bp[(size_t)b * NUM_G + tid], sbp[tid]);
}

// ---------------------------------------------------------------- loss pass (override fused)
__global__ void __launch_bounds__(256) loss_pass_kernel(
        const float* __restrict__ loc_data,
        const float* __restrict__ conf_data,
        const float* __restrict__ priors,
        const float* __restrict__ targets,
        const float* __restrict__ bto,
        const unsigned char* __restrict__ bti,
        const unsigned long long* __restrict__ bp,
        float* __restrict__ lc,
        unsigned int* __restrict__ row_pos,
        Globals* __restrict__ g) {
    int b   = blockIdx.y;
    int tid = threadIdx.x;
    int i   = blockIdx.x * blockDim.x + tid;

    __shared__ unsigned int sIdx[NUM_G];
    if (tid < NUM_G)
        sIdx[tid] = 0xFFFFFFFFu - (unsigned int)(bp[(size_t)b * NUM_G + tid] & 0xFFFFFFFFull);
    __syncthreads();

    float ll = 0.f, pc = 0.f; unsigned int cnt = 0u;
    if (i < NUM_P) {
        float ov = bto[(size_t)b * NUM_P + i];
        int   j  = (int)bti[(size_t)b * NUM_P + i];
        // apply per-gt best-prior overrides (later j wins, like the reference's scatter)
        #pragma unroll
        for (int jj = 0; jj < NUM_G; ++jj)
            if (sIdx[jj] == (unsigned int)i) { ov = 2.0f; j = jj; }

        const float* tg = targets + (size_t)(b * NUM_G + j) * 11;
        bool pos = ov >= THR;
        int label = (int)tg[10];
        int conf_t = pos ? (label + 1) : 0;

        const float* cd = conf_data + (size_t)(b * NUM_P + i) * NUM_C;
        float cv[NUM_C];
        #pragma unroll
        for (int c = 0; c < NUM_C; ++c) cv[c] = cd[c];
        float mx = cv[0];
        #pragma unroll
        for (int c = 1; c < NUM_C; ++c) mx = fmaxf(mx, cv[c]);
        float s = 0.f;
        float tgt = cv[0];
        #pragma unroll
        for (int c = 0; c < NUM_C; ++c) {
            s += __expf(cv[c] - mx);
            if (c == conf_t) tgt = cv[c];
        }
        float lse = __logf(s) + mx;
        float lca = lse - tgt;
        lc[(size_t)b * NUM_P + i] = pos ? 0.f : lca;

        if (pos) {
            cnt = 1u; pc = lca;
            float pcx = priors[i * 4 + 0], pcy = priors[i * 4 + 1];
            float pw  = priors[i * 4 + 2], ph  = priors[i * 4 + 3];
            float m0 = tg[0], m1 = tg[1], m2 = tg[2], m3 = tg[3];
            float t[10];
            t[0] = ((m0 + m2) * 0.5f - pcx) / (0.1f * pw);
            t[1] = ((m1 + m3) * 0.5f - pcy) / (0.1f * ph);
            t[2] = logf((m2 - m0) / pw) / 0.2f;
            t[3] = logf((m3 - m1) / ph) / 0.2f;
            t[4] = logf(tg[4] / pw + 0.1f) / 0.2f;
            t[5] = logf(tg[5] / ph + 0.1f) / 0.2f;
            t[6] = logf(tg[6] / pw + 0.1f) / 0.2f;
            t[7] = logf(tg[7] / ph + 0.1f) / 0.2f;
            t[8] = (tg[8] - pcx) / (0.1f * pw);
            t[9] = (tg[9] - pcy) / (0.1f * ph);
            const float* ld = loc_data + (size_t)(b * NUM_P + i) * 10;
            #pragma unroll
            for (int d = 0; d < 10; ++d) {
                float df = ld[d] - t[d];
                float ad = fabsf(df);
                ll += (ad < 1.f) ? 0.5f * df * df : (ad - 0.5f);
            }
        }
    }

    for (int off = 32; off > 0; off >>= 1) {
        ll  += __shfl_down(ll, (unsigned)off, 64);
        pc  += __shfl_down(pc, (unsigned)off, 64);
        cnt += __shfl_down(cnt, (unsigned)off, 64);
    }
    __shared__ float wll[4], wpc[4];
    __shared__ unsigned int wcnt[4];
    int wave = tid >> 6;
    if ((tid & 63) == 0) { wll[wave] = ll; wpc[wave] = pc; wcnt[wave] = cnt; }
    __syncthreads();
    if (tid == 0) {
        float a = 0.f, c = 0.f; unsigned int n = 0u;
        #pragma unroll
        for (int w = 0; w < 4; ++w) { a += wll[w]; c += wpc[w]; n += wcnt[w]; }
        atomicAdd(&g->loss_l, a);
        atomicAdd(&g->loss_c, c);          // positive-CE part goes straight in
        atomicAdd(&g->npos, (float)n);
        atomicAdd(&row_pos[b], n);
    }
}

// ---------------------------------------------------------------- per-row top-k radix select (parallel scan)
__global__ void __launch_bounds__(SEL_T) select_kernel(
        const float* __restrict__ lc,
        const unsigned int* __restrict__ row_pos,
        Globals* __restrict__ g,
        float* __restrict__ out) {
    int b   = blockIdx.x;
    int tid = threadIdx.x;
    int wv  = tid >> 6;

    __shared__ unsigned int su[NUM_P];
    __shared__ unsigned int whist[SEL_W * 257];
    __shared__ unsigned int stot[256];
    __shared__ unsigned int sbuf0[256], sbuf1[256];
    __shared__ unsigned int s_prefix;
    __shared__ int s_kk;
    __shared__ float wsum[SEL_W];

    for (int idx = tid; idx < NUM_P; idx += SEL_T)
        su[idx] = f2u(lc[(size_t)b * NUM_P + idx]);

    int npos = (int)row_pos[b];
    int k = 3 * npos; if (k > NUM_P - 1) k = NUM_P - 1;

    float negsum = 0.f;
    if (k > 0) {
        if (tid == 0) { s_prefix = 0u; s_kk = k; }
        __syncthreads();

        for (int pass = 0; pass < 4; ++pass) {
            int shift = 24 - 8 * pass;
            for (int x = tid; x < SEL_W * 257; x += SEL_T) whist[x] = 0u;
            __syncthreads();
            unsigned int prefix = s_prefix;
            int kkc = s_kk;
            unsigned int hmask = (pass == 0) ? 0u : (0xFFFFFFFFu << (shift + 8));
            for (int idx = tid; idx < NUM_P; idx += SEL_T) {
                unsigned int u = su[idx];
                if ((u & hmask) == prefix)
                    atomicAdd(&whist[wv * 257 + ((u >> shift) & 255u)], 1u);
            }
            __syncthreads();
            if (tid < 256) {
                unsigned int t = 0;
                #pragma unroll
                for (int w = 0; w < SEL_W; ++w) t += whist[w * 257 + tid];
                stot[tid] = t;
                sbuf0[tid] = t;
            }
            __syncthreads();
            // suffix inclusive scan (Hillis-Steele)
            unsigned int* src = sbuf0;
            unsigned int* dst = sbuf1;
            for (int off = 1; off < 256; off <<= 1) {
                if (tid < 256)
                    dst[tid] = src[tid] + ((tid + off < 256) ? src[tid + off] : 0u);
                __syncthreads();
                unsigned int* tmp = src; src = dst; dst = tmp;
            }
            if (tid < 256) {
                unsigned int Sself = src[tid];
                unsigned int Snext = Sself - stot[tid];
                if ((int)Snext < kkc && kkc <= (int)Sself) {
                    s_prefix = prefix | ((unsigned int)tid << shift);
                    s_kk = kkc - (int)Snext;
                }
            }
            __syncthreads();
        }

        unsigned int Tu = s_prefix;
        int m = s_kk;
        float local = 0.f;
        for (int idx = tid; idx < NUM_P; idx += SEL_T) {
            unsigned int u = su[idx];
            if (u > Tu) local += u2f(u);
        }
        for (int off = 32; off > 0; off >>= 1)
            local += __shfl_down(local, (unsigned)off, 64);
        if ((tid & 63) == 0) wsum[wv] = local;
        __syncthreads();
        if (tid == 0) {
            float ssum = 0.f;
            #pragma unroll
            for (int w = 0; w < SEL_W; ++w) ssum += wsum[w];
            negsum = ssum + (float)m * u2f(Tu);
        }
    }

    if (tid == 0) {
        if (negsum != 0.f) atomicAdd(&g->loss_c, negsum);
        __threadfence();
        unsigned int t = atomicAdd(&g->ticket, 1u);
        if (t == NUM_B - 1) {
            float gl = atomicAdd(&g->loss_l, 0.f);
            float gc = atomicAdd(&g->loss_c, 0.f);
            float gn = atomicAdd(&g->npos, 0.f);
            out[0] = gl / gn;
            out[1] = gc / gn;
        }
    }
}

extern "C" void kernel_launch(void* const* d_in, const int* in_sizes, int n_in,
                              void* d_out, int out_size, void* d_ws, size_t ws_size,
                              hipStream_t stream) {
    const float* loc_data  = (const float*)d_in[0];
    const float* conf_data = (const float*)d_in[1];
    const float* priors    = (const float*)d_in[2];
    const float* targets   = (const float*)d_in[3];
    float* out = (float*)d_out;

    char* ws = (char*)d_ws;
    size_t off = 0;
    float* lc  = (float*)(ws + off); off += (size_t)NUM_B * NUM_P * sizeof(float);
    float* bto = (float*)(ws + off); off += (size_t)NUM_B * NUM_P * sizeof(float);
    unsigned char* bti = (unsigned char*)(ws + off);
    off += ((size_t)NUM_B * NUM_P + 255) & ~255ull;
    unsigned long long* bp = (unsigned long long*)(ws + off);
    off += (size_t)NUM_B * NUM_G * sizeof(unsigned long long);
    unsigned int* row_pos = (unsigned int*)(ws + off); off += NUM_B * sizeof(unsigned int);
    Globals* g = (Globals*)(ws + off); off += sizeof(Globals);

    const int PB = (NUM_P + 255) / 256;  // 35

    init_kernel<<<8, 256, 0, stream>>>(bp, row_pos, g);
    match_kernel<<<dim3(PB, NUM_B), 256, 0, stream>>>(priors, targets, bto, bti, bp);
    loss_pass_kernel<<<dim3(PB, NUM_B), 256, 0, stream>>>(
        loc_data, conf_data, priors, targets, bto, bti, bp,
        lc, row_pos, g);
    select_kernel<<<NUM_B, SEL_T, 0, stream>>>(lc, row_pos, g, out);
}

// Round 3
// 233.327 us; speedup vs baseline: 1.5856x; 1.5856x over previous
//
#include <hip/hip_runtime.h>
#include <stdint.h>

#define NUM_B 128
#define NUM_P 8732
#define NUM_G 16
#define NUM_C 21
#define THR 0.5f
#define SEL_T 512
#define SEL_W (SEL_T / 64)

struct Globals {
    unsigned int ticket;
};

__device__ __forceinline__ unsigned int f2u(float f) {
    unsigned int b = __float_as_uint(f);
    return (b & 0x80000000u) ? ~b : (b | 0x80000000u);
}
__device__ __forceinline__ float u2f(unsigned int u) {
    unsigned int b = (u & 0x80000000u) ? (u & 0x7FFFFFFFu) : ~u;
    return __uint_as_float(b);
}

// ---------------------------------------------------------------- init ws
__global__ void init_kernel(unsigned long long* __restrict__ bp,
                            float* __restrict__ row_loss_l,
                            unsigned int* __restrict__ row_pos,
                            float* __restrict__ row_posc,
                            Globals* __restrict__ g) {
    int idx = blockIdx.x * blockDim.x + threadIdx.x;
    if (idx < NUM_B * NUM_G) bp[idx] = 0ull;
    if (idx < NUM_B) {
        row_loss_l[idx] = 0.f;
        row_pos[idx]    = 0u;
        row_posc[idx]   = 0.f;
    }
    if (idx == 0) g->ticket = 0u;
}

// ---------------------------------------------------------------- matching
__global__ void __launch_bounds__(256) match_kernel(
        const float* __restrict__ priors,
        const float* __restrict__ targets,
        float* __restrict__ bto, unsigned char* __restrict__ bti,
        unsigned long long* __restrict__ bp) {
    int b   = blockIdx.y;
    int tid = threadIdx.x;
    int i   = blockIdx.x * blockDim.x + tid;
    int lane = tid & 63;

    __shared__ float tg[NUM_G][4];
    __shared__ float tarea[NUM_G];
    __shared__ unsigned long long sbp[NUM_G];

    if (tid < NUM_G * 4) {
        int j = tid >> 2, d = tid & 3;
        tg[j][d] = targets[(size_t)(b * NUM_G + j) * 11 + d];
    }
    if (tid < NUM_G) sbp[tid] = 0ull;
    __syncthreads();
    if (tid < NUM_G) tarea[tid] = (tg[tid][2] - tg[tid][0]) * (tg[tid][3] - tg[tid][1]);
    __syncthreads();

    float iou[NUM_G];
    bool valid = (i < NUM_P);
    float best = -1.0f; int bestj = 0;
    if (valid) {
        float4 pr = ((const float4*)priors)[i];
        float bx1 = pr.x - pr.z * 0.5f, by1 = pr.y - pr.w * 0.5f;
        float bx2 = pr.x + pr.z * 0.5f, by2 = pr.y + pr.w * 0.5f;
        float areaB = (bx2 - bx1) * (by2 - by1);
        #pragma unroll
        for (int j = 0; j < NUM_G; ++j) {
            float dx = fminf(tg[j][2], bx2) - fmaxf(tg[j][0], bx1);
            float dy = fminf(tg[j][3], by2) - fmaxf(tg[j][1], by1);
            dx = fmaxf(dx, 0.f); dy = fmaxf(dy, 0.f);
            float inter = dx * dy;
            iou[j] = inter / (tarea[j] + areaB - inter);
            if (iou[j] > best) { best = iou[j]; bestj = j; }  // strict > => first-index
        }
        bto[(size_t)b * NUM_P + i] = best;
        bti[(size_t)b * NUM_P + i] = (unsigned char)bestj;
    } else {
        #pragma unroll
        for (int j = 0; j < NUM_G; ++j) iou[j] = -1.0f;
    }

    // per-gt wave max (float shfl) + ballot leader -> one 64b atomic per gt per wave
    #pragma unroll
    for (int j = 0; j < NUM_G; ++j) {
        float m = iou[j];
        #pragma unroll
        for (int s = 1; s < 64; s <<= 1)
            m = fmaxf(m, __shfl_xor(m, s, 64));
        unsigned long long tied = __ballot(iou[j] == m);
        int leader = __ffsll((unsigned long long)tied) - 1;
        if (lane == leader && valid) {
            unsigned long long pk = ((unsigned long long)f2u(iou[j]) << 32) |
                                    (unsigned long long)(0xFFFFFFFFu - (unsigned int)i);
            atomicMax(&sbp[j], pk);
        }
    }
    __syncthreads();
    if (tid < NUM_G) atomicMax(&bp[(size_t)b * NUM_G + tid], sbp[tid]);
}

// ---------------------------------------------------------------- loss pass (override fused)
__global__ void __launch_bounds__(256) loss_pass_kernel(
        const float* __restrict__ loc_data,
        const float* __restrict__ conf_data,
        const float* __restrict__ priors,
        const float* __restrict__ targets,
        const float* __restrict__ bto,
        const unsigned char* __restrict__ bti,
        const unsigned long long* __restrict__ bp,
        float* __restrict__ lc,
        float* __restrict__ row_loss_l,
        unsigned int* __restrict__ row_pos,
        float* __restrict__ row_posc) {
    int b    = blockIdx.y;
    int tid  = threadIdx.x;
    int base = blockIdx.x * 256;
    int i    = base + tid;

    __shared__ float sconf[256 * NUM_C];   // 21504 B, coalesced staging
    __shared__ unsigned int sIdx[NUM_G];

    int cnt_p = NUM_P - base; if (cnt_p > 256) cnt_p = 256;
    const float* cbase = conf_data + ((size_t)b * NUM_P + base) * NUM_C;
    for (int x = tid; x < cnt_p * NUM_C; x += 256) sconf[x] = cbase[x];
    if (tid < NUM_G)
        sIdx[tid] = 0xFFFFFFFFu - (unsigned int)(bp[(size_t)b * NUM_G + tid] & 0xFFFFFFFFull);
    __syncthreads();

    float ll = 0.f, pc = 0.f; unsigned int cnt = 0u;
    if (i < NUM_P) {
        float ov = bto[(size_t)b * NUM_P + i];
        int   j  = (int)bti[(size_t)b * NUM_P + i];
        // apply per-gt best-prior overrides (later j wins, like the reference's scatter)
        #pragma unroll
        for (int jj = 0; jj < NUM_G; ++jj)
            if (sIdx[jj] == (unsigned int)i) { ov = 2.0f; j = jj; }

        const float* tg = targets + (size_t)(b * NUM_G + j) * 11;
        bool pos = ov >= THR;
        int label = (int)tg[10];
        int conf_t = pos ? (label + 1) : 0;

        const float* cv = &sconf[tid * NUM_C];   // gcd(21,32)=1 -> conflict-free
        float mx = cv[0];
        #pragma unroll
        for (int c = 1; c < NUM_C; ++c) mx = fmaxf(mx, cv[c]);
        float s = 0.f;
        #pragma unroll
        for (int c = 0; c < NUM_C; ++c) s += __expf(cv[c] - mx);
        float lse = __logf(s) + mx;
        float lca = lse - cv[conf_t];
        lc[(size_t)b * NUM_P + i] = pos ? 0.f : lca;

        if (pos) {
            cnt = 1u; pc = lca;
            float4 pr = ((const float4*)priors)[i];
            float m0 = tg[0], m1 = tg[1], m2 = tg[2], m3 = tg[3];
            float t[10];
            t[0] = ((m0 + m2) * 0.5f - pr.x) / (0.1f * pr.z);
            t[1] = ((m1 + m3) * 0.5f - pr.y) / (0.1f * pr.w);
            t[2] = logf((m2 - m0) / pr.z) / 0.2f;
            t[3] = logf((m3 - m1) / pr.w) / 0.2f;
            t[4] = logf(tg[4] / pr.z + 0.1f) / 0.2f;
            t[5] = logf(tg[5] / pr.w + 0.1f) / 0.2f;
            t[6] = logf(tg[6] / pr.z + 0.1f) / 0.2f;
            t[7] = logf(tg[7] / pr.w + 0.1f) / 0.2f;
            t[8] = (tg[8] - pr.x) / (0.1f * pr.z);
            t[9] = (tg[9] - pr.y) / (0.1f * pr.w);
            const float* ld = loc_data + (size_t)(b * NUM_P + i) * 10;
            #pragma unroll
            for (int d = 0; d < 10; ++d) {
                float df = ld[d] - t[d];
                float ad = fabsf(df);
                ll += (ad < 1.f) ? 0.5f * df * df : (ad - 0.5f);
            }
        }
    }

    for (int off = 32; off > 0; off >>= 1) {
        ll  += __shfl_down(ll, (unsigned)off, 64);
        pc  += __shfl_down(pc, (unsigned)off, 64);
        cnt += __shfl_down(cnt, (unsigned)off, 64);
    }
    __shared__ float wll[4], wpc[4];
    __shared__ unsigned int wcnt[4];
    int wave = tid >> 6;
    if ((tid & 63) == 0) { wll[wave] = ll; wpc[wave] = pc; wcnt[wave] = cnt; }
    __syncthreads();
    if (tid == 0) {
        float a = 0.f, c = 0.f; unsigned int n = 0u;
        #pragma unroll
        for (int w = 0; w < 4; ++w) { a += wll[w]; c += wpc[w]; n += wcnt[w]; }
        // per-row accumulators: 128 distinct addresses, <=35-way contention
        atomicAdd(&row_loss_l[b], a);
        atomicAdd(&row_posc[b], c);
        atomicAdd(&row_pos[b], n);
    }
}

// ---------------------------------------------------------------- per-row top-k radix select (parallel scan)
__global__ void __launch_bounds__(SEL_T) select_kernel(
        const float* __restrict__ lc,
        float* __restrict__ row_loss_l,
        unsigned int* __restrict__ row_pos,
        const float* __restrict__ row_posc,
        float* __restrict__ row_loss_c,
        Globals* __restrict__ g,
        float* __restrict__ out) {
    int b   = blockIdx.x;
    int tid = threadIdx.x;
    int wv  = tid >> 6;

    __shared__ unsigned int su[NUM_P];
    __shared__ unsigned int whist[SEL_W * 257];
    __shared__ unsigned int stot[256];
    __shared__ unsigned int sbuf0[256], sbuf1[256];
    __shared__ unsigned int s_prefix;
    __shared__ int s_kk;
    __shared__ float wsum[SEL_W];
    __shared__ int s_last;

    for (int idx = tid; idx < NUM_P; idx += SEL_T)
        su[idx] = f2u(lc[(size_t)b * NUM_P + idx]);

    int npos = (int)row_pos[b];
    int k = 3 * npos; if (k > NUM_P - 1) k = NUM_P - 1;

    float negsum = 0.f;
    if (k > 0) {
        if (tid == 0) { s_prefix = 0u; s_kk = k; }
        __syncthreads();

        for (int pass = 0; pass < 4; ++pass) {
            int shift = 24 - 8 * pass;
            for (int x = tid; x < SEL_W * 257; x += SEL_T) whist[x] = 0u;
            __syncthreads();
            unsigned int prefix = s_prefix;
            int kkc = s_kk;
            unsigned int hmask = (pass == 0) ? 0u : (0xFFFFFFFFu << (shift + 8));
            for (int idx = tid; idx < NUM_P; idx += SEL_T) {
                unsigned int u = su[idx];
                if ((u & hmask) == prefix)
                    atomicAdd(&whist[wv * 257 + ((u >> shift) & 255u)], 1u);
            }
            __syncthreads();
            if (tid < 256) {
                unsigned int t = 0;
                #pragma unroll
                for (int w = 0; w < SEL_W; ++w) t += whist[w * 257 + tid];
                stot[tid] = t;
                sbuf0[tid] = t;
            }
            __syncthreads();
            // suffix inclusive scan (Hillis-Steele)
            unsigned int* src = sbuf0;
            unsigned int* dst = sbuf1;
            for (int off = 1; off < 256; off <<= 1) {
                if (tid < 256)
                    dst[tid] = src[tid] + ((tid + off < 256) ? src[tid + off] : 0u);
                __syncthreads();
                unsigned int* tmp = src; src = dst; dst = tmp;
            }
            if (tid < 256) {
                unsigned int Sself = src[tid];
                unsigned int Snext = Sself - stot[tid];
                if ((int)Snext < kkc && kkc <= (int)Sself) {
                    s_prefix = prefix | ((unsigned int)tid << shift);
                    s_kk = kkc - (int)Snext;
                }
            }
            __syncthreads();
        }

        unsigned int Tu = s_prefix;
        int m = s_kk;
        float local = 0.f;
        for (int idx = tid; idx < NUM_P; idx += SEL_T) {
            unsigned int u = su[idx];
            if (u > Tu) local += u2f(u);
        }
        for (int off = 32; off > 0; off >>= 1)
            local += __shfl_down(local, (unsigned)off, 64);
        if ((tid & 63) == 0) wsum[wv] = local;
        __syncthreads();
        if (tid == 0) {
            float ssum = 0.f;
            #pragma unroll
            for (int w = 0; w < SEL_W; ++w) ssum += wsum[w];
            negsum = ssum + (float)m * u2f(Tu);
        }
    }

    if (tid == 0) {
        row_loss_c[b] = row_posc[b] + negsum;
        __threadfence();
        unsigned int t = atomicAdd(&g->ticket, 1u);
        s_last = (t == NUM_B - 1) ? 1 : 0;
    }
    __syncthreads();

    if (s_last) {
        // last block: reduce the 128 per-row results. atomic reads -> coherent.
        float l = 0.f, c = 0.f, n = 0.f;
        if (tid < NUM_B) {
            l = atomicAdd(&row_loss_l[tid], 0.f);
            c = atomicAdd(&row_loss_c[tid], 0.f);
            n = (float)atomicAdd(&row_pos[tid], 0u);
        }
        for (int off = 32; off > 0; off >>= 1) {
            l += __shfl_down(l, (unsigned)off, 64);
            c += __shfl_down(c, (unsigned)off, 64);
            n += __shfl_down(n, (unsigned)off, 64);
        }
        __shared__ float fl[2], fc[2], fn[2];
        if (tid < NUM_B && (tid & 63) == 0) { fl[wv] = l; fc[wv] = c; fn[wv] = n; }
        __syncthreads();
        if (tid == 0) {
            float L = fl[0] + fl[1], C = fc[0] + fc[1], N = fn[0] + fn[1];
            out[0] = L / N;
            out[1] = C / N;
        }
    }
}

extern "C" void kernel_launch(void* const* d_in, const int* in_sizes, int n_in,
                              void* d_out, int out_size, void* d_ws, size_t ws_size,
                              hipStream_t stream) {
    const float* loc_data  = (const float*)d_in[0];
    const float* conf_data = (const float*)d_in[1];
    const float* priors    = (const float*)d_in[2];
    const float* targets   = (const float*)d_in[3];
    float* out = (float*)d_out;

    char* ws = (char*)d_ws;
    size_t off = 0;
    float* lc  = (float*)(ws + off); off += (size_t)NUM_B * NUM_P * sizeof(float);
    float* bto = (float*)(ws + off); off += (size_t)NUM_B * NUM_P * sizeof(float);
    unsigned char* bti = (unsigned char*)(ws + off);
    off += ((size_t)NUM_B * NUM_P + 255) & ~255ull;
    unsigned long long* bp = (unsigned long long*)(ws + off);
    off += (size_t)NUM_B * NUM_G * sizeof(unsigned long long);
    float* row_loss_l = (float*)(ws + off); off += NUM_B * sizeof(float);
    unsigned int* row_pos = (unsigned int*)(ws + off); off += NUM_B * sizeof(unsigned int);
    float* row_posc   = (float*)(ws + off); off += NUM_B * sizeof(float);
    float* row_loss_c = (float*)(ws + off); off += NUM_B * sizeof(float);
    Globals* g = (Globals*)(ws + off); off += sizeof(Globals);

    const int PB = (NUM_P + 255) / 256;  // 35

    init_kernel<<<8, 256, 0, stream>>>(bp, row_loss_l, row_pos, row_posc, g);
    match_kernel<<<dim3(PB, NUM_B), 256, 0, stream>>>(priors, targets, bto, bti, bp);
    loss_pass_kernel<<<dim3(PB, NUM_B), 256, 0, stream>>>(
        loc_data, conf_data, priors, targets, bto, bti, bp,
        lc, row_loss_l, row_pos, row_posc);
    select_kernel<<<NUM_B, SEL_T, 0, stream>>>(
        lc, row_loss_l, row_pos, row_posc, row_loss_c, g, out);
}